// Round 3
// baseline (689.745 us; speedup 1.0000x reference)
//
#include <hip/hip_runtime.h>
#include <hip/hip_bf16.h>

// PerformerAttention (FAVOR+ exp kernel), B=2 L=8192 D=1024 H=16 DH=64 M=266.
// Inputs/outputs are FLOAT32 (per reference dtypes); internal compute bf16 MFMA.
// Pipeline: conv weights->bf16; gemm_a32 (f32 A staged+converted, bf16 W via
// global_load_lds) -> Qm/Km/Vm bf16; hk max -> kstab; kv kernel (fused
// proj_k/exp/k' -> k'^T v); kv transpose; out kernel (fused proj_q/exp/q' ->
// q'@kv, /denominator) -> ctx bf16; gemm_a16 (bf16 A, f32 out) -> d_out.
// Scratch: Qm=d_out[0:32MB), Vm=d_out[32:64MB) (both dead before final GEMM
// overwrites d_out). ws usage 45.5 MB.

using bf16 = __hip_bfloat16;

typedef short s4v __attribute__((ext_vector_type(4)));   // 4 x bf16 bits
typedef short s8v __attribute__((ext_vector_type(8)));   // 8 x bf16 bits (4 VGPRs)
typedef float f4v __attribute__((ext_vector_type(4)));   // MFMA accumulator

#define MFMA16(a, b, c) __builtin_amdgcn_mfma_f32_16x16x32_bf16((a), (b), (c), 0, 0, 0)

// async global->LDS, 16B per lane; LDS dest is wave-uniform base + lane*16
#define GLD16(gp, lp)                                                      \
  __builtin_amdgcn_global_load_lds(                                        \
      (__attribute__((address_space(1))) void*)(gp),                       \
      (__attribute__((address_space(3))) void*)(lp), 16, 0, 0)

__device__ __forceinline__ float b2f(bf16 x) { return __bfloat162float(x); }
__device__ __forceinline__ bf16 f2b(float x) { return __float2bfloat16(x); }
__device__ __forceinline__ short f2bs(float x) {
  bf16 h = __float2bfloat16(x);
  short s; __builtin_memcpy(&s, &h, 2); return s;
}
__device__ __forceinline__ float braw(short u) {
  unsigned int t = ((unsigned int)(unsigned short)u) << 16;
  float f; __builtin_memcpy(&f, &t, 4); return f;
}
// clamped exp: true args <= ~10; clamp keeps any upstream bug finite
__device__ __forceinline__ float cexp(float x) { return __expf(fminf(x, 30.f)); }
__device__ __forceinline__ f4v f4zero() {
  f4v z; z[0] = 0.f; z[1] = 0.f; z[2] = 0.f; z[3] = 0.f; return z;
}
__device__ __forceinline__ s8v s8zero() {
  s8v z;
#pragma unroll
  for (int i = 0; i < 8; i++) z[i] = 0;
  return z;
}

#define SCALE_QK 0.1767766952966369f   // 1024^-0.25
#define NCONST   0.06131393394849658f  // 266^-0.5
#define KEPS     1e-4f

// ---------------------------------------------------------------------------
// f32 -> bf16 conversion (weights), n divisible by 4
// ---------------------------------------------------------------------------
__global__ __launch_bounds__(256)
void convk(const float* __restrict__ s, bf16* __restrict__ d, int n) {
  const int i = (blockIdx.x * 256 + threadIdx.x) * 4;
  if (i + 3 < n) {
    const float4 f = *(const float4*)(s + i);
    s4v p;
    p[0] = f2bs(f.x); p[1] = f2bs(f.y); p[2] = f2bs(f.z); p[3] = f2bs(f.w);
    *(s4v*)(d + i) = p;
  }
}

// ---------------------------------------------------------------------------
// C_bf16[16384x1024] = (A_f32[16384x1024] @ W_bf16^T + bias_f32) * scale
// 128x128 tile, BK=32, 4 waves 2x2, 4x4 16x16x32 MFMA per wave.
// A staged manually (float4 loads + pack + ds_write), W staged via GLD16.
// ---------------------------------------------------------------------------
__global__ __launch_bounds__(256, 2)
void gemm_a32(const float* __restrict__ A, const bf16* __restrict__ W,
              const float* __restrict__ bias, bf16* __restrict__ C,
              float scale) {
  __shared__ __align__(16) bf16 sA[128 * 32];
  __shared__ __align__(16) bf16 sB[128 * 32];
  const int tid = threadIdx.x;
  const int wave = tid >> 6, lane = tid & 63, quad = lane >> 4, l16 = lane & 15;
  const int wm = (wave & 1) * 64, wn = (wave >> 1) * 64;
  const size_t row0 = (size_t)blockIdx.x * 128, col0 = (size_t)blockIdx.y * 128;
  // A staging: 2 threads/row, 16 k-elements each
  const int ar = tid >> 1, ac = (tid & 1) * 16;
  const float* gA = A + (row0 + ar) * 1024 + ac;
  // B staging: GLD16, 4 threads/row, 8 bf16 each
  const int ldr = tid >> 2, ldc8 = (tid & 3) * 8;
  const bf16* gB = W + (col0 + ldr) * 1024 + ldc8;

  f4v acc[4][4];
#pragma unroll
  for (int i = 0; i < 4; i++)
#pragma unroll
    for (int j = 0; j < 4; j++) acc[i][j] = f4zero();

  for (int k0 = 0; k0 < 1024; k0 += 32) {
    GLD16(gB + k0,         &sB[wave * 512]);
    GLD16(gB + 65536 + k0, &sB[2048 + wave * 512]);
    {
      const float4 f0 = *(const float4*)(gA + k0);
      const float4 f1 = *(const float4*)(gA + k0 + 4);
      const float4 f2 = *(const float4*)(gA + k0 + 8);
      const float4 f3 = *(const float4*)(gA + k0 + 12);
      s8v p0, p1;
      p0[0] = f2bs(f0.x); p0[1] = f2bs(f0.y); p0[2] = f2bs(f0.z); p0[3] = f2bs(f0.w);
      p0[4] = f2bs(f1.x); p0[5] = f2bs(f1.y); p0[6] = f2bs(f1.z); p0[7] = f2bs(f1.w);
      p1[0] = f2bs(f2.x); p1[1] = f2bs(f2.y); p1[2] = f2bs(f2.z); p1[3] = f2bs(f2.w);
      p1[4] = f2bs(f3.x); p1[5] = f2bs(f3.y); p1[6] = f2bs(f3.z); p1[7] = f2bs(f3.w);
      *(s8v*)&sA[ar * 32 + ac]     = p0;
      *(s8v*)&sA[ar * 32 + ac + 8] = p1;
    }
    __syncthreads();
    s8v af[4], bfr[4];
#pragma unroll
    for (int i = 0; i < 4; i++)
      af[i] = *(const s8v*)&sA[(wm + i * 16 + l16) * 32 + quad * 8];
#pragma unroll
    for (int j = 0; j < 4; j++)
      bfr[j] = *(const s8v*)&sB[(wn + j * 16 + l16) * 32 + quad * 8];
#pragma unroll
    for (int i = 0; i < 4; i++)
#pragma unroll
      for (int j = 0; j < 4; j++) acc[i][j] = MFMA16(af[i], bfr[j], acc[i][j]);
    __syncthreads();
  }
#pragma unroll
  for (int j = 0; j < 4; j++) {
    const int col = wn + j * 16 + l16;
    const float bv = bias[col0 + col];
#pragma unroll
    for (int i = 0; i < 4; i++) {
      const size_t rbase = row0 + wm + i * 16 + quad * 4;
#pragma unroll
      for (int r = 0; r < 4; r++)
        C[(rbase + r) * 1024 + col0 + col] = f2b((acc[i][j][r] + bv) * scale);
    }
  }
}

// ---------------------------------------------------------------------------
// Cf32[16384x1024] = A_bf16[16384x1024] @ W_bf16^T + bias_f32   (final GEMM)
// ---------------------------------------------------------------------------
__global__ __launch_bounds__(256, 2)
void gemm_a16(const bf16* __restrict__ A, const bf16* __restrict__ W,
              const float* __restrict__ bias, float* __restrict__ C) {
  __shared__ __align__(16) bf16 sA[128 * 32];
  __shared__ __align__(16) bf16 sB[128 * 32];
  const int tid = threadIdx.x;
  const int wave = tid >> 6, lane = tid & 63, quad = lane >> 4, l16 = lane & 15;
  const int wm = (wave & 1) * 64, wn = (wave >> 1) * 64;
  const size_t row0 = (size_t)blockIdx.x * 128, col0 = (size_t)blockIdx.y * 128;
  const int ldr = tid >> 2, ldc8 = (tid & 3) * 8;
  const bf16* gA = A + (row0 + ldr) * 1024 + ldc8;
  const bf16* gB = W + (col0 + ldr) * 1024 + ldc8;

  f4v acc[4][4];
#pragma unroll
  for (int i = 0; i < 4; i++)
#pragma unroll
    for (int j = 0; j < 4; j++) acc[i][j] = f4zero();

  for (int k0 = 0; k0 < 1024; k0 += 32) {
    GLD16(gA + k0,         &sA[wave * 512]);
    GLD16(gA + 65536 + k0, &sA[2048 + wave * 512]);
    GLD16(gB + k0,         &sB[wave * 512]);
    GLD16(gB + 65536 + k0, &sB[2048 + wave * 512]);
    __syncthreads();
    s8v af[4], bfr[4];
#pragma unroll
    for (int i = 0; i < 4; i++)
      af[i] = *(const s8v*)&sA[(wm + i * 16 + l16) * 32 + quad * 8];
#pragma unroll
    for (int j = 0; j < 4; j++)
      bfr[j] = *(const s8v*)&sB[(wn + j * 16 + l16) * 32 + quad * 8];
#pragma unroll
    for (int i = 0; i < 4; i++)
#pragma unroll
      for (int j = 0; j < 4; j++) acc[i][j] = MFMA16(af[i], bfr[j], acc[i][j]);
    __syncthreads();
  }
#pragma unroll
  for (int j = 0; j < 4; j++) {
    const int col = wn + j * 16 + l16;
    const float bv = bias[col0 + col];
#pragma unroll
    for (int i = 0; i < 4; i++) {
      const size_t rbase = row0 + wm + i * 16 + quad * 4;
#pragma unroll
      for (int r = 0; r < 4; r++)
        C[(rbase + r) * 1024 + col0 + col] = acc[i][j][r] + bv;
    }
  }
}

// ---------------------------------------------------------------------------
// Per (token,head) h_k = -0.5*||k||^2 (Kmat already scaled); block max -> bmax
// ---------------------------------------------------------------------------
__global__ __launch_bounds__(256)
void hk_max(const bf16* __restrict__ Kmat, float* __restrict__ bmax) {
  const int tid = threadIdx.x;
  const int idx = blockIdx.x * 256 + tid;   // (row<<4)|head, 262144 total
  const bf16* p = Kmat + (size_t)(idx >> 4) * 1024 + (idx & 15) * 64;
  float s = 0.f;
#pragma unroll
  for (int i = 0; i < 8; i++) {
    s8v v = *(const s8v*)(p + i * 8);
#pragma unroll
    for (int e = 0; e < 8; e++) { float x = braw(v[e]); s += x * x; }
  }
  float h = -0.5f * s;
#pragma unroll
  for (int off = 32; off > 0; off >>= 1) h = fmaxf(h, __shfl_down(h, off, 64));
  __shared__ float wmax[4];
  if ((tid & 63) == 0) wmax[tid >> 6] = h;
  __syncthreads();
  if (tid == 0)
    bmax[blockIdx.x] = fmaxf(fmaxf(wmax[0], wmax[1]), fmaxf(wmax[2], wmax[3]));
}

__global__ __launch_bounds__(256)
void kred(const float* __restrict__ bmax, float* __restrict__ kstab) {
  const int tid = threadIdx.x;
  float m = -3.0e38f;
  for (int i = tid; i < 1024; i += 256) m = fmaxf(m, bmax[i]);
#pragma unroll
  for (int off = 32; off > 0; off >>= 1) m = fmaxf(m, __shfl_down(m, off, 64));
  __shared__ float wmax[4];
  if ((tid & 63) == 0) wmax[tid >> 6] = m;
  __syncthreads();
  if (tid == 0)
    *kstab = fmaxf(fmaxf(wmax[0], wmax[1]), fmaxf(wmax[2], wmax[3]));
}

// ---------------------------------------------------------------------------
// kv kernel: per (b,h), 512-row chunk in 8 sub-chunks of 64 rows.
//   proj_k = Kchunk @ W_feat^T (MFMA, K=64), k' = nc*(exp(h_k+proj-kstab)+eps)*mask,
//   transpose k' through LDS (stride 88), kv += k'^T @ v (MFMA, K=64),
//   register accumulators, one atomicAdd pass at end. ksum alongside.
// ---------------------------------------------------------------------------
__global__ __launch_bounds__(256, 2)
void kv_kernel(const bf16* __restrict__ Kmat, const bf16* __restrict__ Vmat,
               const bf16* __restrict__ Wf, const float* __restrict__ mask,
               const float* __restrict__ kstab, float* __restrict__ kv,
               float* __restrict__ ksum) {
  __shared__ __align__(16) bf16 sK[64 * 64];
  __shared__ __align__(16) bf16 sVt[64 * 88];    // V transposed [dh][row]
  __shared__ __align__(16) bf16 sKp[272 * 88];   // k' transposed [feat][row]
  __shared__ float sHp[256];
  __shared__ float sH[64];
  __shared__ float sMask[64];
  __shared__ float sKsum[272];

  const int tid = threadIdx.x;
  const int wave = tid >> 6, lane = tid & 63, quad = lane >> 4, l16 = lane & 15;
  const int ci = blockIdx.x, bh = blockIdx.y;
  const int b = bh >> 4, h = bh & 15;
  const int l0 = ci * 512;
  const float kst = *kstab;

  for (int i = tid; i < 272; i += 256) sKsum[i] = 0.f;

  f4v acc[17];
#pragma unroll
  for (int j = 0; j < 17; j++) acc[j] = f4zero();

  const int vr = tid >> 3, vc8 = (tid & 7) * 8;  // staging (32 rows / call)
  const int hr = tid & 63, hp = tid >> 6;        // h-partial

  for (int sc = 0; sc < 8; sc++) {
    const size_t grow = (size_t)b * 8192 + l0 + sc * 64;
    // stage K sub-chunk (async direct-to-LDS)
    GLD16(Kmat + (grow + vr) * 1024 + h * 64 + vc8,      &sK[wave * 512]);
    GLD16(Kmat + (grow + 32 + vr) * 1024 + h * 64 + vc8, &sK[2048 + wave * 512]);
    // stage V transposed
#pragma unroll
    for (int i = 0; i < 2; i++) {
      const unsigned short* g =
          (const unsigned short*)(Vmat + (grow + 32 * i + vr) * 1024 + h * 64 + vc8);
      ushort4 a = *(const ushort4*)g;
      ushort4 c = *(const ushort4*)(g + 4);
      const int r = 32 * i + vr;
      unsigned short* sv = (unsigned short*)sVt;
      sv[(vc8 + 0) * 88 + r] = a.x; sv[(vc8 + 1) * 88 + r] = a.y;
      sv[(vc8 + 2) * 88 + r] = a.z; sv[(vc8 + 3) * 88 + r] = a.w;
      sv[(vc8 + 4) * 88 + r] = c.x; sv[(vc8 + 5) * 88 + r] = c.y;
      sv[(vc8 + 6) * 88 + r] = c.z; sv[(vc8 + 7) * 88 + r] = c.w;
    }
    // h_k partials (re-read K from global, L2-hot) + mask (f32)
    {
      const bf16* g = Kmat + (grow + hr) * 1024 + h * 64 + hp * 16;
      s8v v0 = *(const s8v*)g;
      s8v v1 = *(const s8v*)(g + 8);
      float s = 0.f;
#pragma unroll
      for (int e = 0; e < 8; e++) {
        float x0 = braw(v0[e]); float x1 = braw(v1[e]);
        s += x0 * x0 + x1 * x1;
      }
      sHp[hp * 64 + hr] = s;
      if (hp == 0) sMask[hr] = mask[grow + hr];
    }
    __syncthreads();
    if (tid < 64)
      sH[tid] = -0.5f * (sHp[tid] + sHp[64 + tid] + sHp[128 + tid] + sHp[192 + tid]);
    __syncthreads();
    // proj_k + k' transform, write transposed
    {
      const s8v aK0 = *(const s8v*)&sK[(wave * 16 + l16) * 64 + quad * 8];
      const s8v aK1 = *(const s8v*)&sK[(wave * 16 + l16) * 64 + 32 + quad * 8];
      const int rb = wave * 16 + quad * 4;
      float hv[4], mv[4];
#pragma unroll
      for (int r = 0; r < 4; r++) { hv[r] = sH[rb + r] - kst; mv[r] = sMask[rb + r]; }
#pragma unroll
      for (int j = 0; j < 17; j++) {
        const int f = j * 16 + l16;
        s8v w0, w1;
        if (f < 266) {
          w0 = *(const s8v*)(Wf + f * 64 + quad * 8);
          w1 = *(const s8v*)(Wf + f * 64 + 32 + quad * 8);
        } else { w0 = s8zero(); w1 = s8zero(); }
        f4v p = f4zero();
        p = MFMA16(aK0, w0, p);
        p = MFMA16(aK1, w1, p);
        if (f < 266) {
          float sk = 0.f;
#pragma unroll
          for (int r = 0; r < 4; r++) {
            float kp = NCONST * (cexp(hv[r] + p[r]) + KEPS) * mv[r];
            sk += kp;
            sKp[f * 88 + rb + r] = f2b(kp);
          }
          atomicAdd(&sKsum[f], sk);
        } else {
#pragma unroll
          for (int r = 0; r < 4; r++) sKp[f * 88 + rb + r] = f2b(0.f);
        }
      }
    }
    __syncthreads();
    // kv += k'^T @ v  (wave = dh-tile, 17 feature tiles, K=64)
    {
      const s8v bV0 = *(const s8v*)&sVt[(wave * 16 + l16) * 88 + quad * 8];
      const s8v bV1 = *(const s8v*)&sVt[(wave * 16 + l16) * 88 + 32 + quad * 8];
#pragma unroll
      for (int j = 0; j < 17; j++) {
        const s8v a0 = *(const s8v*)&sKp[(j * 16 + l16) * 88 + quad * 8];
        const s8v a1 = *(const s8v*)&sKp[(j * 16 + l16) * 88 + 32 + quad * 8];
        acc[j] = MFMA16(a0, bV0, acc[j]);
        acc[j] = MFMA16(a1, bV1, acc[j]);
      }
    }
    __syncthreads();
  }
  // write out: C layout col(=dh)=l16, row(=feat offset)=quad*4+r
  const int dh = wave * 16 + l16;
#pragma unroll
  for (int j = 0; j < 17; j++) {
    const int fb = j * 16 + quad * 4;
#pragma unroll
    for (int r = 0; r < 4; r++)
      atomicAdd(&kv[((size_t)bh * 272 + fb + r) * 64 + dh], acc[j][r]);
  }
  for (int i = tid; i < 272; i += 256) atomicAdd(&ksum[(size_t)bh * 272 + i], sKsum[i]);
}

// kv [32][272][64] f32 -> kvT [32][64][288] bf16 (zero-padded features)
__global__ __launch_bounds__(256)
void kvt_kernel(const float* __restrict__ kv, bf16* __restrict__ kvT) {
  const int idx = blockIdx.x * 256 + threadIdx.x;  // < 589824
  const int f = idx % 288;
  const int t2 = idx / 288;
  const int dh = t2 & 63;
  const int bh = t2 >> 6;
  float v = 0.f;
  if (f < 272) v = kv[((size_t)bh * 272 + f) * 64 + dh];
  kvT[idx] = f2b(v);
}

// ---------------------------------------------------------------------------
// out kernel: per (b,h), 64-row chunk.
//   proj_q (MFMA) -> q' = nc*(exp(proj)+eps) into LDS (stride 296),
//   denominator d = q'.ksum (+stabilizer), out = q' @ kv (MFMA, K=288), ctx=out/d
// ---------------------------------------------------------------------------
__global__ __launch_bounds__(256, 2)
void out_kernel(const bf16* __restrict__ Qmat, const bf16* __restrict__ Wf,
                const bf16* __restrict__ kvT, const float* __restrict__ ksum,
                bf16* __restrict__ ctx) {
  __shared__ __align__(16) bf16 sQ[64 * 64];
  __shared__ __align__(16) bf16 sQp[64 * 296];
  __shared__ float sKs[272];
  __shared__ float sDp[256];
  __shared__ float sRd[64];

  const int tid = threadIdx.x;
  const int wave = tid >> 6, lane = tid & 63, quad = lane >> 4, l16 = lane & 15;
  const int ci = blockIdx.x, bh = blockIdx.y;
  const int b = bh >> 4, h = bh & 15;
  const size_t grow = (size_t)b * 8192 + ci * 64;

  const int vr = tid >> 3, vc8 = (tid & 7) * 8;
  GLD16(Qmat + (grow + vr) * 1024 + h * 64 + vc8,      &sQ[wave * 512]);
  GLD16(Qmat + (grow + 32 + vr) * 1024 + h * 64 + vc8, &sQ[2048 + wave * 512]);

  for (int i = tid; i < 272; i += 256) sKs[i] = ksum[(size_t)bh * 272 + i];
  {  // zero feature pad [272,288)
    const int r = tid >> 2, c = tid & 3;
#pragma unroll
    for (int cc = 0; cc < 4; cc++) sQp[r * 296 + 272 + c * 4 + cc] = f2b(0.f);
  }
  __syncthreads();

  const s8v aQ0 = *(const s8v*)&sQ[(wave * 16 + l16) * 64 + quad * 8];
  const s8v aQ1 = *(const s8v*)&sQ[(wave * 16 + l16) * 64 + 32 + quad * 8];
  const int rb = wave * 16 + quad * 4;
#pragma unroll
  for (int j = 0; j < 17; j++) {
    const int f = j * 16 + l16;
    s8v w0, w1;
    if (f < 266) {
      w0 = *(const s8v*)(Wf + f * 64 + quad * 8);
      w1 = *(const s8v*)(Wf + f * 64 + 32 + quad * 8);
    } else { w0 = s8zero(); w1 = s8zero(); }
    f4v p = f4zero();
    p = MFMA16(aQ0, w0, p);
    p = MFMA16(aQ1, w1, p);
#pragma unroll
    for (int r = 0; r < 4; r++) {
      float qp = (f < 266) ? NCONST * (cexp(p[r]) + KEPS) : 0.f;
      sQp[(rb + r) * 296 + f] = f2b(qp);
    }
  }
  __syncthreads();
  {  // denominator partials
    const int r = tid & 63, part = tid >> 6;
    float s = 0.f;
    for (int f = part * 68; f < part * 68 + 68; f++)
      s += b2f(sQp[r * 296 + f]) * sKs[f];
    sDp[part * 64 + r] = s;
  }
  __syncthreads();
  if (tid < 64) {
    float d = sDp[tid] + sDp[64 + tid] + sDp[128 + tid] + sDp[192 + tid];
    if (fabsf(d) <= 1e-6f) d += 2e-6f;
    sRd[tid] = 1.f / d;
  }
  __syncthreads();
  // out = q' @ kv   (wave = dh-tile, 4 row tiles, K=288)
  f4v acc[4];
#pragma unroll
  for (int mt = 0; mt < 4; mt++) acc[mt] = f4zero();
  const bf16* kvb = kvT + (size_t)bh * 64 * 288 + (wave * 16 + l16) * 288;
#pragma unroll
  for (int kk = 0; kk < 9; kk++) {
    const s8v bfr = *(const s8v*)(kvb + kk * 32 + quad * 8);
#pragma unroll
    for (int mt = 0; mt < 4; mt++) {
      const s8v a = *(const s8v*)&sQp[(mt * 16 + l16) * 296 + kk * 32 + quad * 8];
      acc[mt] = MFMA16(a, bfr, acc[mt]);
    }
  }
  const int col = wave * 16 + l16;
#pragma unroll
  for (int mt = 0; mt < 4; mt++) {
#pragma unroll
    for (int r = 0; r < 4; r++) {
      const int row = mt * 16 + quad * 4 + r;
      ctx[(grow + row) * 1024 + h * 64 + col] = f2b(acc[mt][r] * sRd[row]);
    }
  }
}

// ---------------------------------------------------------------------------
// workspace layout (bytes) — 45.5 MB. Km at 0, aliased by ctx after kv_kernel.
// Qm = d_out[0:32MB), Vm = d_out[32:64MB) (f32 d_out is 64MB; both dead
// before final GEMM overwrites d_out).
// ---------------------------------------------------------------------------
static const size_t OFF_KM    = 0;                       // 33554432
static const size_t OFF_CTX   = 0;                       // alias Km
static const size_t OFF_WQ    = 33554432;                // 2097152 each
static const size_t OFF_WK    = OFF_WQ + 2097152;
static const size_t OFF_WV    = OFF_WK + 2097152;
static const size_t OFF_WO    = OFF_WV + 2097152;
static const size_t OFF_WF    = OFF_WO + 2097152;        // 34048 -> pad 65536
static const size_t OFF_KV    = OFF_WF + 65536;          // 2228224
static const size_t OFF_KSUM  = OFF_KV + 2228224;        // 34816
static const size_t OFF_KVT   = OFF_KSUM + 34816;        // 1179648
static const size_t OFF_BMAX  = OFF_KVT + 1179648;       // 4096
static const size_t OFF_KSTAB = OFF_BMAX + 4096;
static const size_t WS_NEEDED = OFF_KSTAB + 16;

extern "C" void kernel_launch(void* const* d_in, const int* in_sizes, int n_in,
                              void* d_out, int out_size, void* d_ws, size_t ws_size,
                              hipStream_t stream) {
  (void)in_sizes; (void)n_in; (void)out_size;
  if (ws_size < WS_NEEDED) return;  // diagnostic: output stays 0
  const float* query = (const float*)d_in[0];
  const float* key_  = (const float*)d_in[1];
  const float* value = (const float*)d_in[2];
  const float* mask  = (const float*)d_in[3];
  const float* Wq = (const float*)d_in[4];
  const float* bq = (const float*)d_in[5];
  const float* Wk = (const float*)d_in[6];
  const float* bk = (const float*)d_in[7];
  const float* Wv = (const float*)d_in[8];
  const float* bv = (const float*)d_in[9];
  const float* Wo = (const float*)d_in[10];
  const float* bo = (const float*)d_in[11];
  const float* Wf = (const float*)d_in[12];

  char* ws = (char*)d_ws;
  bf16*  Qm   = (bf16*)d_out;                          // d_out[0:32MB)
  bf16*  Vm   = (bf16*)((char*)d_out + 33554432);      // d_out[32:64MB)
  bf16*  Km   = (bf16*)(ws + OFF_KM);
  bf16*  ctxb = (bf16*)(ws + OFF_CTX);
  bf16*  wqb  = (bf16*)(ws + OFF_WQ);
  bf16*  wkb  = (bf16*)(ws + OFF_WK);
  bf16*  wvb  = (bf16*)(ws + OFF_WV);
  bf16*  wob  = (bf16*)(ws + OFF_WO);
  bf16*  wfb  = (bf16*)(ws + OFF_WF);
  float* kv    = (float*)(ws + OFF_KV);
  float* ksum  = (float*)(ws + OFF_KSUM);
  bf16*  kvT   = (bf16*)(ws + OFF_KVT);
  float* bmax  = (float*)(ws + OFF_BMAX);
  float* kstab = (float*)(ws + OFF_KSTAB);
  float* outp  = (float*)d_out;

  const dim3 blk(256);
  convk<<<dim3(1024), blk, 0, stream>>>(Wq, wqb, 1048576);
  convk<<<dim3(1024), blk, 0, stream>>>(Wk, wkb, 1048576);
  convk<<<dim3(1024), blk, 0, stream>>>(Wv, wvb, 1048576);
  convk<<<dim3(1024), blk, 0, stream>>>(Wo, wob, 1048576);
  convk<<<dim3(17),   blk, 0, stream>>>(Wf, wfb, 17024);

  gemm_a32<<<dim3(128, 8), blk, 0, stream>>>(query, wqb, bq, Qm, SCALE_QK);
  gemm_a32<<<dim3(128, 8), blk, 0, stream>>>(key_,  wkb, bk, Km, SCALE_QK);
  gemm_a32<<<dim3(128, 8), blk, 0, stream>>>(value, wvb, bv, Vm, 1.0f);
  hk_max<<<dim3(1024), blk, 0, stream>>>(Km, bmax);
  kred<<<dim3(1), blk, 0, stream>>>(bmax, kstab);
  hipMemsetAsync(ws + OFF_KV, 0, 2228224 + 34816, stream);  // kv + ksum
  kv_kernel<<<dim3(16, 32), blk, 0, stream>>>(Km, Vm, wfb, mask, kstab, kv, ksum);
  kvt_kernel<<<dim3(2304), blk, 0, stream>>>(kv, kvT);
  out_kernel<<<dim3(128, 32), blk, 0, stream>>>(Qm, wfb, kvT, ksum, ctxb);
  gemm_a16<<<dim3(128, 8), blk, 0, stream>>>(ctxb, wob, bo, outp);
}

// Round 4
// 627.914 us; speedup vs baseline: 1.0985x; 1.0985x over previous
//
#include <hip/hip_runtime.h>
#include <hip/hip_bf16.h>

// PerformerAttention (FAVOR+ exp kernel), B=2 L=8192 D=1024 H=16 DH=64 M=266.
// Inputs/outputs FLOAT32; internal compute bf16 MFMA.
// R4: barrier-free kv_kernel (wave-partitioned features, Wf fragments in
// registers, K/V fragments direct-from-global / wave-local LDS, no
// __syncthreads, conflict-free LDS strides). Weight converts merged.

using bf16 = __hip_bfloat16;

typedef short s4v __attribute__((ext_vector_type(4)));   // 4 x bf16 bits
typedef short s8v __attribute__((ext_vector_type(8)));   // 8 x bf16 bits (4 VGPRs)
typedef float f4v __attribute__((ext_vector_type(4)));   // MFMA accumulator

#define MFMA16(a, b, c) __builtin_amdgcn_mfma_f32_16x16x32_bf16((a), (b), (c), 0, 0, 0)

// async global->LDS, 16B per lane; LDS dest is wave-uniform base + lane*16
#define GLD16(gp, lp)                                                      \
  __builtin_amdgcn_global_load_lds(                                        \
      (__attribute__((address_space(1))) void*)(gp),                       \
      (__attribute__((address_space(3))) void*)(lp), 16, 0, 0)

__device__ __forceinline__ float b2f(bf16 x) { return __bfloat162float(x); }
__device__ __forceinline__ bf16 f2b(float x) { return __float2bfloat16(x); }
__device__ __forceinline__ short f2bs(float x) {
  bf16 h = __float2bfloat16(x);
  short s; __builtin_memcpy(&s, &h, 2); return s;
}
__device__ __forceinline__ float braw(short u) {
  unsigned int t = ((unsigned int)(unsigned short)u) << 16;
  float f; __builtin_memcpy(&f, &t, 4); return f;
}
// clamped exp: true args <= ~10; clamp keeps any upstream bug finite
__device__ __forceinline__ float cexp(float x) { return __expf(fminf(x, 30.f)); }
__device__ __forceinline__ f4v f4zero() {
  f4v z; z[0] = 0.f; z[1] = 0.f; z[2] = 0.f; z[3] = 0.f; return z;
}
__device__ __forceinline__ s8v s8zero() {
  s8v z;
#pragma unroll
  for (int i = 0; i < 8; i++) z[i] = 0;
  return z;
}

#define SCALE_QK 0.1767766952966369f   // 1024^-0.25
#define NCONST   0.06131393394849658f  // 266^-0.5
#define KEPS     1e-4f

// ---------------------------------------------------------------------------
// f32 -> bf16 weight converts: 4x 1048576-elem matrices in one dispatch
// ---------------------------------------------------------------------------
__global__ __launch_bounds__(256)
void convw4(const float* __restrict__ s0, const float* __restrict__ s1,
            const float* __restrict__ s2, const float* __restrict__ s3,
            bf16* __restrict__ d0, bf16* __restrict__ d1,
            bf16* __restrict__ d2, bf16* __restrict__ d3) {
  const int w = blockIdx.y;
  const float* s = (w == 0) ? s0 : (w == 1) ? s1 : (w == 2) ? s2 : s3;
  bf16* d = (w == 0) ? d0 : (w == 1) ? d1 : (w == 2) ? d2 : d3;
  const int i = (blockIdx.x * 256 + threadIdx.x) * 4;
  const float4 f = *(const float4*)(s + i);
  s4v p;
  p[0] = f2bs(f.x); p[1] = f2bs(f.y); p[2] = f2bs(f.z); p[3] = f2bs(f.w);
  *(s4v*)(d + i) = p;
}

__global__ __launch_bounds__(256)
void convk(const float* __restrict__ s, bf16* __restrict__ d, int n) {
  const int i = (blockIdx.x * 256 + threadIdx.x) * 4;
  if (i + 3 < n) {
    const float4 f = *(const float4*)(s + i);
    s4v p;
    p[0] = f2bs(f.x); p[1] = f2bs(f.y); p[2] = f2bs(f.z); p[3] = f2bs(f.w);
    *(s4v*)(d + i) = p;
  }
}

// ---------------------------------------------------------------------------
// C_bf16[16384x1024] = (A_f32[16384x1024] @ W_bf16^T + bias_f32) * scale
// 128x128 tile, BK=32, 4 waves 2x2, 4x4 16x16x32 MFMA per wave.
// ---------------------------------------------------------------------------
__global__ __launch_bounds__(256, 2)
void gemm_a32(const float* __restrict__ A, const bf16* __restrict__ W,
              const float* __restrict__ bias, bf16* __restrict__ C,
              float scale) {
  __shared__ __align__(16) bf16 sA[128 * 32];
  __shared__ __align__(16) bf16 sB[128 * 32];
  const int tid = threadIdx.x;
  const int wave = tid >> 6, lane = tid & 63, quad = lane >> 4, l16 = lane & 15;
  const int wm = (wave & 1) * 64, wn = (wave >> 1) * 64;
  const size_t row0 = (size_t)blockIdx.x * 128, col0 = (size_t)blockIdx.y * 128;
  const int ar = tid >> 1, ac = (tid & 1) * 16;
  const float* gA = A + (row0 + ar) * 1024 + ac;
  const int ldr = tid >> 2, ldc8 = (tid & 3) * 8;
  const bf16* gB = W + (col0 + ldr) * 1024 + ldc8;

  f4v acc[4][4];
#pragma unroll
  for (int i = 0; i < 4; i++)
#pragma unroll
    for (int j = 0; j < 4; j++) acc[i][j] = f4zero();

  for (int k0 = 0; k0 < 1024; k0 += 32) {
    GLD16(gB + k0,         &sB[wave * 512]);
    GLD16(gB + 65536 + k0, &sB[2048 + wave * 512]);
    {
      const float4 f0 = *(const float4*)(gA + k0);
      const float4 f1 = *(const float4*)(gA + k0 + 4);
      const float4 f2 = *(const float4*)(gA + k0 + 8);
      const float4 f3 = *(const float4*)(gA + k0 + 12);
      s8v p0, p1;
      p0[0] = f2bs(f0.x); p0[1] = f2bs(f0.y); p0[2] = f2bs(f0.z); p0[3] = f2bs(f0.w);
      p0[4] = f2bs(f1.x); p0[5] = f2bs(f1.y); p0[6] = f2bs(f1.z); p0[7] = f2bs(f1.w);
      p1[0] = f2bs(f2.x); p1[1] = f2bs(f2.y); p1[2] = f2bs(f2.z); p1[3] = f2bs(f2.w);
      p1[4] = f2bs(f3.x); p1[5] = f2bs(f3.y); p1[6] = f2bs(f3.z); p1[7] = f2bs(f3.w);
      *(s8v*)&sA[ar * 32 + ac]     = p0;
      *(s8v*)&sA[ar * 32 + ac + 8] = p1;
    }
    __syncthreads();
    s8v af[4], bfr[4];
#pragma unroll
    for (int i = 0; i < 4; i++)
      af[i] = *(const s8v*)&sA[(wm + i * 16 + l16) * 32 + quad * 8];
#pragma unroll
    for (int j = 0; j < 4; j++)
      bfr[j] = *(const s8v*)&sB[(wn + j * 16 + l16) * 32 + quad * 8];
#pragma unroll
    for (int i = 0; i < 4; i++)
#pragma unroll
      for (int j = 0; j < 4; j++) acc[i][j] = MFMA16(af[i], bfr[j], acc[i][j]);
    __syncthreads();
  }
#pragma unroll
  for (int j = 0; j < 4; j++) {
    const int col = wn + j * 16 + l16;
    const float bv = bias[col0 + col];
#pragma unroll
    for (int i = 0; i < 4; i++) {
      const size_t rbase = row0 + wm + i * 16 + quad * 4;
#pragma unroll
      for (int r = 0; r < 4; r++)
        C[(rbase + r) * 1024 + col0 + col] = f2b((acc[i][j][r] + bv) * scale);
    }
  }
}

// ---------------------------------------------------------------------------
// Cf32[16384x1024] = A_bf16 @ W_bf16^T + bias_f32   (final GEMM)
// ---------------------------------------------------------------------------
__global__ __launch_bounds__(256, 2)
void gemm_a16(const bf16* __restrict__ A, const bf16* __restrict__ W,
              const float* __restrict__ bias, float* __restrict__ C) {
  __shared__ __align__(16) bf16 sA[128 * 32];
  __shared__ __align__(16) bf16 sB[128 * 32];
  const int tid = threadIdx.x;
  const int wave = tid >> 6, lane = tid & 63, quad = lane >> 4, l16 = lane & 15;
  const int wm = (wave & 1) * 64, wn = (wave >> 1) * 64;
  const size_t row0 = (size_t)blockIdx.x * 128, col0 = (size_t)blockIdx.y * 128;
  const int ldr = tid >> 2, ldc8 = (tid & 3) * 8;
  const bf16* gA = A + (row0 + ldr) * 1024 + ldc8;
  const bf16* gB = W + (col0 + ldr) * 1024 + ldc8;

  f4v acc[4][4];
#pragma unroll
  for (int i = 0; i < 4; i++)
#pragma unroll
    for (int j = 0; j < 4; j++) acc[i][j] = f4zero();

  for (int k0 = 0; k0 < 1024; k0 += 32) {
    GLD16(gA + k0,         &sA[wave * 512]);
    GLD16(gA + 65536 + k0, &sA[2048 + wave * 512]);
    GLD16(gB + k0,         &sB[wave * 512]);
    GLD16(gB + 65536 + k0, &sB[2048 + wave * 512]);
    __syncthreads();
    s8v af[4], bfr[4];
#pragma unroll
    for (int i = 0; i < 4; i++)
      af[i] = *(const s8v*)&sA[(wm + i * 16 + l16) * 32 + quad * 8];
#pragma unroll
    for (int j = 0; j < 4; j++)
      bfr[j] = *(const s8v*)&sB[(wn + j * 16 + l16) * 32 + quad * 8];
#pragma unroll
    for (int i = 0; i < 4; i++)
#pragma unroll
      for (int j = 0; j < 4; j++) acc[i][j] = MFMA16(af[i], bfr[j], acc[i][j]);
    __syncthreads();
  }
#pragma unroll
  for (int j = 0; j < 4; j++) {
    const int col = wn + j * 16 + l16;
    const float bv = bias[col0 + col];
#pragma unroll
    for (int i = 0; i < 4; i++) {
      const size_t rbase = row0 + wm + i * 16 + quad * 4;
#pragma unroll
      for (int r = 0; r < 4; r++)
        C[(rbase + r) * 1024 + col0 + col] = acc[i][j][r] + bv;
    }
  }
}

// ---------------------------------------------------------------------------
// Per (token,head) h_k = -0.5*||k||^2; block max -> bmax; then global reduce
// ---------------------------------------------------------------------------
__global__ __launch_bounds__(256)
void hk_max(const bf16* __restrict__ Kmat, float* __restrict__ bmax) {
  const int tid = threadIdx.x;
  const int idx = blockIdx.x * 256 + tid;
  const bf16* p = Kmat + (size_t)(idx >> 4) * 1024 + (idx & 15) * 64;
  float s = 0.f;
#pragma unroll
  for (int i = 0; i < 8; i++) {
    s8v v = *(const s8v*)(p + i * 8);
#pragma unroll
    for (int e = 0; e < 8; e++) { float x = braw(v[e]); s += x * x; }
  }
  float h = -0.5f * s;
#pragma unroll
  for (int off = 32; off > 0; off >>= 1) h = fmaxf(h, __shfl_down(h, off, 64));
  __shared__ float wmax[4];
  if ((tid & 63) == 0) wmax[tid >> 6] = h;
  __syncthreads();
  if (tid == 0)
    bmax[blockIdx.x] = fmaxf(fmaxf(wmax[0], wmax[1]), fmaxf(wmax[2], wmax[3]));
}

__global__ __launch_bounds__(256)
void kred(const float* __restrict__ bmax, float* __restrict__ kstab) {
  const int tid = threadIdx.x;
  float m = -3.0e38f;
  for (int i = tid; i < 1024; i += 256) m = fmaxf(m, bmax[i]);
#pragma unroll
  for (int off = 32; off > 0; off >>= 1) m = fmaxf(m, __shfl_down(m, off, 64));
  __shared__ float wmax[4];
  if ((tid & 63) == 0) wmax[tid >> 6] = m;
  __syncthreads();
  if (tid == 0)
    *kstab = fmaxf(fmaxf(wmax[0], wmax[1]), fmaxf(wmax[2], wmax[3]));
}

// ---------------------------------------------------------------------------
// kv kernel v2 — BARRIER-FREE. Per (b,h), 512 tokens per block, 16 iters of 32.
// Waves partition feature tiles {5,4,4,4}. Per 16-token group:
//   proj^T = Wf(A, registers) x K^T(B, direct global) MFMA;
//   h_k from the same K fragments via shfl_xor; k' -> wave-local LDS
//   transpose buffer (stride 40). Per 32 tokens: kv += k'^T x V MFMA with
//   V from wave-local natural-layout LDS (stride 66, conflict-free).
// Register accumulators; one atomicAdd pass at end. ksum via shfl-reduce.
// ---------------------------------------------------------------------------
__global__ __launch_bounds__(256, 2)
void kv_kernel2(const bf16* __restrict__ Kmat, const bf16* __restrict__ Vmat,
                const bf16* __restrict__ Wf, const float* __restrict__ mask,
                const float* __restrict__ kstab, float* __restrict__ kv,
                float* __restrict__ ksum) {
  __shared__ __align__(16) bf16 sV[4][32 * 66];     // per-wave V natural
  __shared__ __align__(16) bf16 sT[4][5][16 * 40];  // per-wave k'^T tiles
  const int tid = threadIdx.x;
  const int wave = tid >> 6, lane = tid & 63, quad = lane >> 4, l16 = lane & 15;
  const int bh = blockIdx.y, b = bh >> 4, h = bh & 15;
  const float kst = *kstab;
  const int NT = (wave == 0) ? 5 : 4;

  // preload Wf A-fragments: lane holds Wf[tile*16+l16][quad*8+j (+32)]
  s8v wf0[5], wf1[5];
#pragma unroll
  for (int t = 0; t < 5; t++) {
    const int f = (wave + t * 4) * 16 + l16;
    if (t < NT && f < 266) {
      wf0[t] = *(const s8v*)(Wf + f * 64 + quad * 8);
      wf1[t] = *(const s8v*)(Wf + f * 64 + 32 + quad * 8);
    } else { wf0[t] = s8zero(); wf1[t] = s8zero(); }
  }

  f4v acc[5][4];
  float ks[5][4];
#pragma unroll
  for (int t = 0; t < 5; t++) {
#pragma unroll
    for (int d = 0; d < 4; d++) acc[t][d] = f4zero();
#pragma unroll
    for (int r = 0; r < 4; r++) ks[t][r] = 0.f;
  }

  const size_t base = (size_t)b * 8192 + blockIdx.x * 512;
  const int svr = lane >> 1, svc = (lane & 1) * 32;
  bf16* sVb = &sV[wave][0];
  const unsigned short* sVu = (const unsigned short*)sVb;

  for (int it = 0; it < 16; it++) {
    const size_t tok0 = base + it * 32;
    // stage V[32 tok][64 dh] -> wave-local LDS, stride 66 (vector writes)
    {
      const bf16* g = Vmat + (tok0 + svr) * 1024 + h * 64 + svc;
#pragma unroll
      for (int c = 0; c < 4; c++)
        *(s8v*)&sVb[svr * 66 + svc + c * 8] = *(const s8v*)(g + c * 8);
    }
    // proj^T + k' for 2 token groups of 16
#pragma unroll
    for (int tg = 0; tg < 2; tg++) {
      const size_t tk = tok0 + tg * 16;
      const bf16* kp = Kmat + (tk + l16) * 1024 + h * 64;
      const s8v bk0 = *(const s8v*)(kp + quad * 8);
      const s8v bk1 = *(const s8v*)(kp + 32 + quad * 8);
      float ss = 0.f;
#pragma unroll
      for (int e = 0; e < 8; e++) {
        float x0 = braw(bk0[e]), x1 = braw(bk1[e]);
        ss += x0 * x0 + x1 * x1;
      }
      ss += __shfl_xor(ss, 16, 64);
      ss += __shfl_xor(ss, 32, 64);
      const float hh = -0.5f * ss - kst;       // h_k - kstab, token l16
      const float mv = mask[tk + l16];
#pragma unroll
      for (int t = 0; t < 5; t++) {
        if (t < NT) {
          f4v p = f4zero();
          p = MFMA16(wf0[t], bk0, p);
          p = MFMA16(wf1[t], bk1, p);
          const int fb = (wave + t * 4) * 16 + quad * 4;
          bf16* buf = &sT[wave][t][0];
#pragma unroll
          for (int r = 0; r < 4; r++) {
            const float kp_ = (fb + r < 266)
                ? NCONST * (cexp(hh + p[r]) + KEPS) * mv : 0.f;
            ks[t][r] += kp_;
            buf[(quad * 4 + r) * 40 + tg * 16 + l16] = f2b(kp_);
          }
        }
      }
    }
    __builtin_amdgcn_wave_barrier();
    // B_V fragments: lane holds V[tok=quad*8+j][dh=d*16+l16], stride-66 reads
    s8v bv[4];
#pragma unroll
    for (int d = 0; d < 4; d++) {
#pragma unroll
      for (int j = 0; j < 8; j++)
        bv[d][j] = (short)sVu[(quad * 8 + j) * 66 + d * 16 + l16];
    }
    // kv += k'^T @ V over the 32-token pair
#pragma unroll
    for (int t = 0; t < 5; t++) {
      if (t < NT) {
        const s8v a = *(const s8v*)&sT[wave][t][l16 * 40 + quad * 8];
#pragma unroll
        for (int d = 0; d < 4; d++) acc[t][d] = MFMA16(a, bv[d], acc[t][d]);
      }
    }
    __builtin_amdgcn_wave_barrier();
  }
  // ksum: reduce over l16 lanes; kv: atomic accumulate (C layout: col=dh=l16,
  // row=feat=quad*4+r)
#pragma unroll
  for (int t = 0; t < 5; t++) {
    if (t < NT) {
      const int fb = (wave + t * 4) * 16 + quad * 4;
#pragma unroll
      for (int r = 0; r < 4; r++) {
        float s = ks[t][r];
        s += __shfl_xor(s, 1, 64);
        s += __shfl_xor(s, 2, 64);
        s += __shfl_xor(s, 4, 64);
        s += __shfl_xor(s, 8, 64);
        if (l16 == 0) atomicAdd(&ksum[(size_t)bh * 272 + fb + r], s);
      }
#pragma unroll
      for (int d = 0; d < 4; d++)
#pragma unroll
        for (int r = 0; r < 4; r++)
          atomicAdd(&kv[((size_t)bh * 272 + fb + r) * 64 + d * 16 + l16],
                    acc[t][d][r]);
    }
  }
}

// kv [32][272][64] f32 -> kvT [32][64][288] bf16 (zero-padded features)
__global__ __launch_bounds__(256)
void kvt_kernel(const float* __restrict__ kv, bf16* __restrict__ kvT) {
  const int idx = blockIdx.x * 256 + threadIdx.x;
  const int f = idx % 288;
  const int t2 = idx / 288;
  const int dh = t2 & 63;
  const int bh = t2 >> 6;
  float v = 0.f;
  if (f < 272) v = kv[((size_t)bh * 272 + f) * 64 + dh];
  kvT[idx] = f2b(v);
}

// ---------------------------------------------------------------------------
// out kernel: per (b,h), 64-row chunk. proj_q -> q' (LDS stride 296),
// denominator, q' @ kv (K=288), ctx = out/d.
// ---------------------------------------------------------------------------
__global__ __launch_bounds__(256, 2)
void out_kernel(const bf16* __restrict__ Qmat, const bf16* __restrict__ Wf,
                const bf16* __restrict__ kvT, const float* __restrict__ ksum,
                bf16* __restrict__ ctx) {
  __shared__ __align__(16) bf16 sQ[64 * 64];
  __shared__ __align__(16) bf16 sQp[64 * 296];
  __shared__ float sKs[272];
  __shared__ float sDp[256];
  __shared__ float sRd[64];

  const int tid = threadIdx.x;
  const int wave = tid >> 6, lane = tid & 63, quad = lane >> 4, l16 = lane & 15;
  const int ci = blockIdx.x, bh = blockIdx.y;
  const int b = bh >> 4, h = bh & 15;
  const size_t grow = (size_t)b * 8192 + ci * 64;

  const int vr = tid >> 3, vc8 = (tid & 7) * 8;
  GLD16(Qmat + (grow + vr) * 1024 + h * 64 + vc8,      &sQ[wave * 512]);
  GLD16(Qmat + (grow + 32 + vr) * 1024 + h * 64 + vc8, &sQ[2048 + wave * 512]);

  for (int i = tid; i < 272; i += 256) sKs[i] = ksum[(size_t)bh * 272 + i];
  {  // zero feature pad [272,288)
    const int r = tid >> 2, c = tid & 3;
#pragma unroll
    for (int cc = 0; cc < 4; cc++) sQp[r * 296 + 272 + c * 4 + cc] = f2b(0.f);
  }
  __syncthreads();

  const s8v aQ0 = *(const s8v*)&sQ[(wave * 16 + l16) * 64 + quad * 8];
  const s8v aQ1 = *(const s8v*)&sQ[(wave * 16 + l16) * 64 + 32 + quad * 8];
  const int rb = wave * 16 + quad * 4;
#pragma unroll
  for (int j = 0; j < 17; j++) {
    const int f = j * 16 + l16;
    s8v w0, w1;
    if (f < 266) {
      w0 = *(const s8v*)(Wf + f * 64 + quad * 8);
      w1 = *(const s8v*)(Wf + f * 64 + 32 + quad * 8);
    } else { w0 = s8zero(); w1 = s8zero(); }
    f4v p = f4zero();
    p = MFMA16(aQ0, w0, p);
    p = MFMA16(aQ1, w1, p);
#pragma unroll
    for (int r = 0; r < 4; r++) {
      float qp = (f < 266) ? NCONST * (cexp(p[r]) + KEPS) : 0.f;
      sQp[(rb + r) * 296 + f] = f2b(qp);
    }
  }
  __syncthreads();
  {  // denominator partials
    const int r = tid & 63, part = tid >> 6;
    float s = 0.f;
    for (int f = part * 68; f < part * 68 + 68; f++)
      s += b2f(sQp[r * 296 + f]) * sKs[f];
    sDp[part * 64 + r] = s;
  }
  __syncthreads();
  if (tid < 64) {
    float d = sDp[tid] + sDp[64 + tid] + sDp[128 + tid] + sDp[192 + tid];
    if (fabsf(d) <= 1e-6f) d += 2e-6f;
    sRd[tid] = 1.f / d;
  }
  __syncthreads();
  f4v acc[4];
#pragma unroll
  for (int mt = 0; mt < 4; mt++) acc[mt] = f4zero();
  const bf16* kvb = kvT + (size_t)bh * 64 * 288 + (wave * 16 + l16) * 288;
#pragma unroll
  for (int kk = 0; kk < 9; kk++) {
    const s8v bfr = *(const s8v*)(kvb + kk * 32 + quad * 8);
#pragma unroll
    for (int mt = 0; mt < 4; mt++) {
      const s8v a = *(const s8v*)&sQp[(mt * 16 + l16) * 296 + kk * 32 + quad * 8];
      acc[mt] = MFMA16(a, bfr, acc[mt]);
    }
  }
  const int col = wave * 16 + l16;
#pragma unroll
  for (int mt = 0; mt < 4; mt++) {
#pragma unroll
    for (int r = 0; r < 4; r++) {
      const int row = mt * 16 + quad * 4 + r;
      ctx[(grow + row) * 1024 + h * 64 + col] = f2b(acc[mt][r] * sRd[row]);
    }
  }
}

// ---------------------------------------------------------------------------
// workspace layout (bytes) — 45.5 MB. Km at 0, aliased by ctx after kv_kernel.
// Qm = d_out[0:32MB), Vm = d_out[32:64MB) (both dead before final GEMM).
// ---------------------------------------------------------------------------
static const size_t OFF_KM    = 0;                       // 33554432
static const size_t OFF_CTX   = 0;                       // alias Km
static const size_t OFF_WQ    = 33554432;                // 2097152 each
static const size_t OFF_WK    = OFF_WQ + 2097152;
static const size_t OFF_WV    = OFF_WK + 2097152;
static const size_t OFF_WO    = OFF_WV + 2097152;
static const size_t OFF_WF    = OFF_WO + 2097152;        // 34048 -> pad 65536
static const size_t OFF_KV    = OFF_WF + 65536;          // 2228224
static const size_t OFF_KSUM  = OFF_KV + 2228224;        // 34816
static const size_t OFF_KVT   = OFF_KSUM + 34816;        // 1179648
static const size_t OFF_BMAX  = OFF_KVT + 1179648;       // 4096
static const size_t OFF_KSTAB = OFF_BMAX + 4096;
static const size_t WS_NEEDED = OFF_KSTAB + 16;

extern "C" void kernel_launch(void* const* d_in, const int* in_sizes, int n_in,
                              void* d_out, int out_size, void* d_ws, size_t ws_size,
                              hipStream_t stream) {
  (void)in_sizes; (void)n_in; (void)out_size;
  if (ws_size < WS_NEEDED) return;  // diagnostic: output stays 0
  const float* query = (const float*)d_in[0];
  const float* key_  = (const float*)d_in[1];
  const float* value = (const float*)d_in[2];
  const float* mask  = (const float*)d_in[3];
  const float* Wq = (const float*)d_in[4];
  const float* bq = (const float*)d_in[5];
  const float* Wk = (const float*)d_in[6];
  const float* bk = (const float*)d_in[7];
  const float* Wv = (const float*)d_in[8];
  const float* bv = (const float*)d_in[9];
  const float* Wo = (const float*)d_in[10];
  const float* bo = (const float*)d_in[11];
  const float* Wf = (const float*)d_in[12];

  char* ws = (char*)d_ws;
  bf16*  Qm   = (bf16*)d_out;                          // d_out[0:32MB)
  bf16*  Vm   = (bf16*)((char*)d_out + 33554432);      // d_out[32:64MB)
  bf16*  Km   = (bf16*)(ws + OFF_KM);
  bf16*  ctxb = (bf16*)(ws + OFF_CTX);
  bf16*  wqb  = (bf16*)(ws + OFF_WQ);
  bf16*  wkb  = (bf16*)(ws + OFF_WK);
  bf16*  wvb  = (bf16*)(ws + OFF_WV);
  bf16*  wob  = (bf16*)(ws + OFF_WO);
  bf16*  wfb  = (bf16*)(ws + OFF_WF);
  float* kv    = (float*)(ws + OFF_KV);
  float* ksum  = (float*)(ws + OFF_KSUM);
  bf16*  kvT   = (bf16*)(ws + OFF_KVT);
  float* bmax  = (float*)(ws + OFF_BMAX);
  float* kstab = (float*)(ws + OFF_KSTAB);
  float* outp  = (float*)d_out;

  const dim3 blk(256);
  convw4<<<dim3(1024, 4), blk, 0, stream>>>(Wq, Wk, Wv, Wo, wqb, wkb, wvb, wob);
  convk<<<dim3(17), blk, 0, stream>>>(Wf, wfb, 17024);

  gemm_a32<<<dim3(128, 8), blk, 0, stream>>>(query, wqb, bq, Qm, SCALE_QK);
  gemm_a32<<<dim3(128, 8), blk, 0, stream>>>(key_,  wkb, bk, Km, SCALE_QK);
  gemm_a32<<<dim3(128, 8), blk, 0, stream>>>(value, wvb, bv, Vm, 1.0f);
  hk_max<<<dim3(1024), blk, 0, stream>>>(Km, bmax);
  kred<<<dim3(1), blk, 0, stream>>>(bmax, kstab);
  hipMemsetAsync(ws + OFF_KV, 0, 2228224 + 34816, stream);  // kv + ksum
  kv_kernel2<<<dim3(16, 32), blk, 0, stream>>>(Km, Vm, wfb, mask, kstab, kv, ksum);
  kvt_kernel<<<dim3(2304), blk, 0, stream>>>(kv, kvT);
  out_kernel<<<dim3(128, 32), blk, 0, stream>>>(Qm, wfb, kvT, ksum, ctxb);
  gemm_a16<<<dim3(128, 8), blk, 0, stream>>>(ctxb, wob, bo, outp);
}